// Round 9
// baseline (39.308 us; speedup 1.0000x reference)
//
#include <hip/hip_runtime.h>

#define NATOMS  1024
#define NB      32
#define WPB     4                  // waves per block
#define BLK     (WPB * 64)         // 256 threads
#define BPBATCH 64                 // blocks per batch
#define WAVES   (BPBATCH * WPB)    // 256 waves per batch
#define PPW     ((NATOMS / 2) / WAVES)  // 2 row-pairs per wave

// Single fused kernel. e = d0*b*exp(p1*(1-b^p2)), class s = t_i+t_j:
//   e = de * exp2(lg + c1*exp2(p2*lg)),  lg = log2|b|,
//   de = d0*e^p1, c1 = -p1*log2(e).   (b=0 -> lg=-inf -> e=0, matches ref.)
// Per-lane t_i values preloaded into registers (fixed index set per lane);
// block partial goes straight to out[b] via one atomicAdd per block.
__global__ __launch_bounds__(BLK) void reax_fused(
    const int*   __restrict__ Z,
    const float* __restrict__ B,
    const float* __restrict__ d0t,
    const float* __restrict__ p1t,
    const float* __restrict__ p2t,
    float*       __restrict__ out)
{
    const int b    = blockIdx.y;
    const int wave = blockIdx.x * WPB + (threadIdx.x >> 6);
    const int lane = threadIdx.x & 63;

    const float LOG2E = 1.4426950408889634f;
    const float d0_0 = d0t[4], d0_1 = d0t[5], d0_2 = d0t[8];
    const float p1_0 = p1t[4], p1_1 = p1t[5], p1_2 = p1t[8];
    const float p2_0 = p2t[4], p2_1 = p2t[5], p2_2 = p2t[8];
    const float de_0 = d0_0 * __builtin_amdgcn_exp2f(p1_0 * LOG2E);
    const float de_1 = d0_1 * __builtin_amdgcn_exp2f(p1_1 * LOG2E);
    const float de_2 = d0_2 * __builtin_amdgcn_exp2f(p1_2 * LOG2E);
    const float c1_0 = -p1_0 * LOG2E, c1_1 = -p1_1 * LOG2E, c1_2 = -p1_2 * LOG2E;

    __shared__ float t_shf[NATOMS];     // atom type as float (0.0 / 1.0)
    const int* Zrow = Z + b * NATOMS;
    for (int i = threadIdx.x; i < NATOMS; i += BLK)
        t_shf[i] = (Zrow[i] == 8) ? 1.0f : 0.0f;
    __syncthreads();

    // Preload this lane's t values for the whole kernel: indices 4*(lane+64k)+c.
    const float4* Trow4 = (const float4*)t_shf;
    const float4 tt0 = Trow4[lane];
    const float4 tt1 = Trow4[lane + 64];
    const float4 tt2 = Trow4[lane + 128];
    const float4 tt3 = Trow4[lane + 192];

    const float* Bb = B + (size_t)b * NATOMS * NATOMS;
    float sum0 = 0.0f, sum1 = 0.0f;

    for (int pp = 0; pp < PPW; ++pp) {
        const int p = wave + pp * WAVES;   // 0..511
        #pragma unroll
        for (int r = 0; r < 2; ++r) {
            const int j = r ? (NATOMS - 1 - p) : p;
            if (j == 0) continue;
            const int tj = (t_shf[j] != 0.0f);
            const float dea = tj ? de_1 : de_0, dde = tj ? (de_2 - de_1) : (de_1 - de_0);
            const float c1a = tj ? c1_1 : c1_0, dc1 = tj ? (c1_2 - c1_1) : (c1_1 - c1_0);
            const float p2a = tj ? p2_1 : p2_0, dp2 = tj ? (p2_2 - p2_1) : (p2_1 - p2_0);

            const float*  Brow  = Bb + (size_t)j * NATOMS;
            const float4* Brow4 = (const float4*)Brow;
            const int nv = j >> 2;

            #define ELEM(xc, tc, acc)                                       \
            {                                                               \
                const float bb  = fabsf(xc);                                \
                const float p2  = fmaf(tc, dp2, p2a);                       \
                const float c1  = fmaf(tc, dc1, c1a);                       \
                const float de  = fmaf(tc, dde, dea);                       \
                const float lg  = __builtin_amdgcn_logf(bb);                \
                const float pw  = __builtin_amdgcn_exp2f(p2 * lg);          \
                const float ex  = __builtin_amdgcn_exp2f(fmaf(c1, pw, lg)); \
                acc = fmaf(de, ex, acc);                                    \
            }

            #define KSTEP(K, TT)                                            \
            {                                                               \
                const int v = lane + 64 * (K);                              \
                if (v < nv) {                                               \
                    const float4 x = Brow4[v];                              \
                    ELEM(x.x, TT.x, sum0) ELEM(x.y, TT.y, sum1)             \
                    ELEM(x.z, TT.z, sum0) ELEM(x.w, TT.w, sum1)             \
                }                                                           \
            }
            KSTEP(0, tt0) KSTEP(1, tt1) KSTEP(2, tt2) KSTEP(3, tt3)
            #undef KSTEP

            // tail: up to 3 elements
            const int i = (nv << 2) + lane;
            if (i < j) {
                ELEM(Brow[i], t_shf[i], sum0)
            }
            #undef ELEM
        }
    }

    float sum = sum0 + sum1;
    #pragma unroll
    for (int off = 32; off; off >>= 1) sum += __shfl_down(sum, off, 64);

    __shared__ float wsum[WPB];
    if (lane == 0) wsum[threadIdx.x >> 6] = sum;
    __syncthreads();
    if (threadIdx.x == 0) {
        const float block_sum = wsum[0] + wsum[1] + wsum[2] + wsum[3];
        atomicAdd(&out[b], -block_sum);   // e_ij carries the leading minus
    }
}

extern "C" void kernel_launch(void* const* d_in, const int* in_sizes, int n_in,
                              void* d_out, int out_size, void* d_ws, size_t ws_size,
                              hipStream_t stream) {
    const int*   Z   = (const int*)  d_in[0];
    const float* B   = (const float*)d_in[1];
    const float* d0t = (const float*)d_in[2];
    const float* p1t = (const float*)d_in[3];
    const float* p2t = (const float*)d_in[4];
    float* out = (float*)d_out;

    hipMemsetAsync(out, 0, NB * sizeof(float), stream);
    dim3 grid(BPBATCH, NB);
    reax_fused<<<grid, BLK, 0, stream>>>(Z, B, d0t, p1t, p2t, out);
}